// Round 11
// baseline (128.526 us; speedup 1.0000x reference)
//
#include <hip/hip_runtime.h>
#include <math.h>

#define N 1024
#define B_ 8
#define T_ 1024
#define WAVES 16
#define NREP 4
#define CHUNKS 32

// ws layout (float index)
#define OFF_SF      0        // 1024 x float2 (element shift factor)
#define OFF_TA      2048     // 16(k1) x 64(lane) x float2 : W_1024^{lane*k1}
#define OFF_TB      4096     // 16(k2) x 4(n3) x float2    : W_64^{n3*k2}
#define OFF_ROWSUM  4224     // 8 x 1024
#define ZERO_START  12416
#define OFF_COLSUMM 12416    // 1024
#define OFF_SUMM2   13440
#define OFF_MAXM    13441
#define OFF_SUMMT   13448    // 8
#define OFF_SUMTT   13456    // 8
#define OFF_COLT    13464    // 8 batches x NREP x 1024
#define WS_END      (OFF_COLT + B_ * NREP * N)

// packed fp32 pair (re,im) — clang lowers <2 x float> arithmetic to v_pk_*_f32
typedef float f2 __attribute__((ext_vector_type(2)));
__device__ __forceinline__ f2 mkf2(float a, float b) { f2 r; r.x = a; r.y = b; return r; }

__device__ __forceinline__ f2 cmulv(f2 a, f2 b) {
    f2 p = mkf2(a.x, a.x) * b;                 // (ax bx, ax by)
    f2 q = mkf2(a.y, a.y) * mkf2(b.y, b.x);    // (ay by, ay bx)
    return mkf2(p.x - q.x, p.y + q.y);
}

// 4-pt DFT (W4 = -i), in place, packed complex
__device__ __forceinline__ void dft4v(f2& a0, f2& a1, f2& a2, f2& a3) {
    f2 e0 = a0 + a2, e1 = a0 - a2, e2 = a1 + a3, e3 = a1 - a3;
    a0 = e0 + e2;
    a2 = e0 - e2;
    a1 = mkf2(e1.x + e3.y, e1.y - e3.x);   // e1 - i*e3
    a3 = mkf2(e1.x - e3.y, e1.y + e3.x);   // e1 + i*e3
}

// 16-pt DFT over register index n (natural order in).
// Output: slot r = 4c+d holds S[k = c+4d]  (digit-swapped order).
__device__ __forceinline__ void dft16v(f2 x[16]) {
    #pragma unroll
    for (int b = 0; b < 4; ++b) dft4v(x[b], x[4 + b], x[8 + b], x[12 + b]);
    const float C1 = 0.9238795325112867f, S1 = 0.3826834323650898f;
    const float C2 = 0.7071067811865476f;
    x[5]  = cmulv(x[5],  mkf2( C1, -S1));   // bc=1
    x[6]  = cmulv(x[6],  mkf2( C2, -C2));   // bc=2
    x[7]  = cmulv(x[7],  mkf2( S1, -C1));   // bc=3
    x[9]  = cmulv(x[9],  mkf2( C2, -C2));   // bc=2
    x[10] = mkf2(x[10].y, -x[10].x);        // bc=4 : * (0,-1)
    x[11] = cmulv(x[11], mkf2(-C2, -C2));   // bc=6
    x[13] = cmulv(x[13], mkf2( S1, -C1));   // bc=3
    x[14] = cmulv(x[14], mkf2(-C2, -C2));   // bc=6
    x[15] = cmulv(x[15], mkf2(-C1,  S1));   // bc=9
    #pragma unroll
    for (int c = 0; c < 4; ++c) dft4v(x[4*c], x[4*c+1], x[4*c+2], x[4*c+3]);
}

__device__ __forceinline__ float wave_sum(float v) {
    #pragma unroll
    for (int o = 32; o > 0; o >>= 1) v += __shfl_down(v, o, 64);
    return v;
}
__device__ __forceinline__ float wave_max(float v) {
    #pragma unroll
    for (int o = 32; o > 0; o >>= 1) v = fmaxf(v, __shfl_down(v, o, 64));
    return v;
}

// DPP quad-perm move (cross-lane within each 4-lane quad), VALU-only
template<int CTRL>
__device__ __forceinline__ float dppf(float x) {
    return __int_as_float(__builtin_amdgcn_update_dpp(
        0, __float_as_int(x), CTRL, 0xF, 0xF, true));
}
#define DPP_XOR1 0xB1   // quad_perm [1,0,3,2]
#define DPP_XOR2 0x4E   // quad_perm [2,3,0,1]

// trig tables: 9 blocks x 256 threads (double sincos; huge sf args need f64)
__global__ __launch_bounds__(256) void k_prep(float* ws) {
    const int e = blockIdx.x * 256 + threadIdx.x;   // 0..2303
    if (e < 1024) {
        double ang = -2.0 * 337.927 * 1.5 * (double)(e - 512);
        double s, c;
        sincos(ang, &s, &c);
        ws[OFF_SF + 2 * e]     = (float)c;
        ws[OFF_SF + 2 * e + 1] = (float)s;
    } else if (e < 2048) {
        int e2 = e - 1024;
        int k1 = e2 >> 6, uu = e2 & 63;
        double ang = -2.0 * M_PI * (double)(uu * k1) / 1024.0;
        double s, c;
        sincos(ang, &s, &c);
        ws[OFF_TA + 2 * e2]     = (float)c;
        ws[OFF_TA + 2 * e2 + 1] = (float)s;
    } else if (e < 2112) {
        int e2 = e - 2048;
        int k2 = e2 >> 2, n3 = e2 & 3;
        double ang = -2.0 * M_PI * (double)(n3 * k2) / 64.0;
        double s, c;
        sincos(ang, &s, &c);
        ws[OFF_TB + 2 * e2]     = (float)c;
        ws[OFF_TB + 2 * e2 + 1] = (float)s;
    }
}

// WG-LAUNCH-RATE A/B (r10 postmortem): five different inner loops all measured
// 40-47 µs -> duration is invariant to block-interior code; the shared constant
// is WORKGROUP COUNT. This round: grid (32,8) = 256 WGs x 1024 threads (16
// waves) = HALF the WGs of r10 with IDENTICAL per-CU wave count (16) and
// identical per-wave row code. If launch-rate-bound, k_row ~46.8 -> ~26-32 µs.
// Wave wid does row m = 16*cnk + wid; (cnk0,wid0) also does m=512.
// Stats tail: block gid scans M rows 4gid..4gid+3 (uniform, each element once).
// waves_per_eu(2,4): the only VGPR-budget config measured spill-free (128 cap).
__global__ __attribute__((amdgpu_flat_work_group_size(T_, T_), amdgpu_waves_per_eu(2, 4)))
void k_row(const float* __restrict__ pred,
           const float* __restrict__ M,
           float* __restrict__ ws) {
    __shared__ f2   Y2[N];            // 8 KB   y interleaved
    __shared__ f2   Ysf[N];           // 8 KB   y * shiftfactor
    __shared__ f2   taL[N];           // 8 KB   W_1024^{u*k1} table
    __shared__ f2   TPh[WAVES][N / 2];// 64 KB  per-wave half transpose buffers
    __shared__ f2   TB2[64];          // 0.5 KB W_64^{n3*k2}
    __shared__ float colAcc[N];       // 4 KB   block column accumulator
    __shared__ float redf[2][WAVES];
    const int t = threadIdx.x;
    const int cnk = blockIdx.x;
    const int b = blockIdx.y;
    const int wid = t >> 6, u = t & 63;

    // ---- staging: y, y*sf, ta table into LDS; colAcc zero ----
    {
        const float* pr = pred + (size_t)b * 2 * N;
        f2 y0 = mkf2(pr[t], pr[N + t]);
        const f2* g = (const f2*)ws;
        Y2[t]  = y0;
        Ysf[t] = cmulv(y0, g[OFF_SF / 2 + t]);
        taL[t] = g[OFF_TA / 2 + t];
        if (t < 64) TB2[t] = g[OFF_TB / 2 + t];
        colAcc[t] = 0.f;
    }
    __syncthreads();

    const int k1u = u >> 2;
    const int n3 = u & 3;
    const int k3 = ((u & 1) << 1) | ((u >> 1) & 1);   // bitrev2(n3)
    const int clane = (k1u | (k3 << 8)) ^ 512;        // output column base (incl. fftshift)
    const bool hi2 = (u & 2) != 0;
    const bool odd = (u & 1) != 0;
    f2* tp = TPh[wid];

    float mtl = 0.f, ttl = 0.f;
    const int nrow = (cnk == 0 && wid == 0) ? 2 : 1;

    for (int rr = 0; rr < nrow; ++rr) {
        const int m = (rr == 0) ? (cnk * WAVES + wid) : 512;
        const int mm = (N - m) & (N - 1);
        const bool domm = (mm != m);
        const float w = domm ? 2.f : 1.f;
        const float mmw = domm ? 1.f : 0.f;

        f2 x[16];
        // phase A: product (ysf[j]*y[s]) + radix-16 over n1 — all LDS, packed
        const int sbase = (u - m + 512) & (N - 1);
        #pragma unroll
        for (int n1 = 0; n1 < 16; ++n1) {
            int j = (n1 << 6) + u;
            int s = (sbase + (n1 << 6)) & (N - 1);
            x[n1] = cmulv(Ysf[j], Y2[s]);
        }
        dft16v(x);
        #pragma unroll
        for (int r = 1; r < 16; ++r) {
            int k1 = ((r & 3) << 2) | (r >> 2);
            x[r] = cmulv(x[r], taL[(k1 << 6) + u]);
        }

        // wave-local transpose in two k1-halves through a 4 KB/wave buffer
        f2 yv[16];
        asm volatile("s_waitcnt lgkmcnt(0)" ::: "memory");   // WAR vs prev row reads
        #pragma unroll
        for (int r = 0; r < 16; ++r) if ((r & 3) < 2) {      // k1 = 0..7
            int k1 = ((r & 3) << 2) | (r >> 2);
            int el = ((k1 & 7) << 6) | (((k1u ^ k1) & 15) << 2) | n3;
            tp[el] = x[r];
        }
        asm volatile("s_waitcnt lgkmcnt(0)" ::: "memory");   // RAW write->read
        if (u < 32) {                                         // lanes with k1u<8
            #pragma unroll
            for (int n2 = 0; n2 < 16; ++n2) {
                int el = ((k1u & 7) << 6) | (((n2 ^ k1u) & 15) << 2) | n3;
                yv[n2] = tp[el];
            }
        }
        asm volatile("s_waitcnt lgkmcnt(0)" ::: "memory");   // reads done before overwrite
        #pragma unroll
        for (int r = 0; r < 16; ++r) if ((r & 3) >= 2) {     // k1 = 8..15
            int k1 = ((r & 3) << 2) | (r >> 2);
            int el = ((k1 & 7) << 6) | (((k1u ^ k1) & 15) << 2) | n3;
            tp[el] = x[r];
        }
        asm volatile("s_waitcnt lgkmcnt(0)" ::: "memory");
        if (u >= 32) {                                        // lanes with k1u>=8
            #pragma unroll
            for (int n2 = 0; n2 < 16; ++n2) {
                int el = ((k1u & 7) << 6) | (((n2 ^ k1u) & 15) << 2) | n3;
                yv[n2] = tp[el];
            }
        }

        // phase B: radix-16 over n2 + W_64^{n3*k2} — packed
        dft16v(yv);
        #pragma unroll
        for (int r = 1; r < 16; ++r) {
            int k2 = ((r & 3) << 2) | (r >> 2);
            yv[r] = cmulv(yv[r], TB2[(k2 << 2) | n3]);
        }

        // phase C: radix-4 across quad lanes (DPP) + magnitude + reductions.
        // M loaded inline (compiler schedules freely) — r8-proven.
        const float* Mrow  = M + (size_t)m * N + clane;
        const float* Mrow2 = M + (size_t)mm * N + clane;
        const float w225 = w * 2.25f;
        float rs = 0.f;
        #pragma unroll
        for (int r = 0; r < 16; ++r) {
            int k2 = ((r & 3) << 2) | (r >> 2);
            float ar = yv[r].x, ai = yv[r].y;
            float br = dppf<DPP_XOR2>(ar), bi = dppf<DPP_XOR2>(ai);
            float zr = hi2 ? (br - ar) : (ar + br);
            float zi = hi2 ? (bi - ai) : (ai + bi);
            float qr = dppf<DPP_XOR1>(zr), qi = dppf<DPP_XOR1>(zi);
            float Xr = odd ? (qr - (hi2 ? zi : zr)) : (zr + (hi2 ? qi : qr));
            float Xi = odd ? (qi + (hi2 ? zr : -zi)) : (zi + (hi2 ? -qr : qi));
            float mag2 = Xr * Xr + Xi * Xi;
            float v = 1.5f * sqrtf(mag2);
            rs  += v;
            ttl += w225 * mag2;                 // w * v^2
            float ms = Mrow[k2 << 4] + mmw * Mrow2[k2 << 4];
            mtl += ms * v;
            int cc = clane + (k2 << 4);
            atomicAdd(&colAcc[cc ^ ((cc >> 4) & 16)], w * v);  // 2-way bank alias: free
        }
        rs = wave_sum(rs);
        if (u == 0) {
            ws[OFF_ROWSUM + (size_t)b * N + m] = rs;
            if (domm) ws[OFF_ROWSUM + (size_t)b * N + mm] = rs;
        }
    }

    // block epilogue: MT/TT block-reduce + colAcc flush (1 global atomic/column)
    mtl = wave_sum(mtl);
    ttl = wave_sum(ttl);
    if (u == 0) { redf[0][wid] = mtl; redf[1][wid] = ttl; }
    __syncthreads();
    if (t == 0) {
        float smt = 0.f, stt = 0.f;
        #pragma unroll
        for (int i = 0; i < WAVES; ++i) { smt += redf[0][i]; stt += redf[1][i]; }
        atomicAdd(&ws[OFF_SUMMT + b], smt);
        atomicAdd(&ws[OFF_SUMTT + b], stt);
    }
    {
        float* colT = ws + OFF_COLT + (size_t)(b * NREP + (cnk & (NREP - 1))) * N;
        atomicAdd(&colT[t], colAcc[t ^ ((t >> 4) & 16)]);
    }

    // ---- uniform M-stats tail: this block scans M rows 4*gid .. 4*gid+3 ----
    {
        const int gid = b * CHUNKS + cnk;            // 0..255
        const float* s0 = M + (size_t)(4 * gid) * N;
        float a0 = s0[t], a1 = s0[N + t], a2 = s0[2 * N + t], a3 = s0[3 * N + t];
        atomicAdd(&ws[OFF_COLSUMM + t], a0 + a1 + a2 + a3);
        float sq = a0 * a0 + a1 * a1 + a2 * a2 + a3 * a3;
        float mx = fmaxf(fmaxf(a0, a1), fmaxf(a2, a3));
        sq = wave_sum(sq);
        mx = wave_max(mx);
        __syncthreads();                              // t0 done reading redf above
        if (u == 0) { redf[0][wid] = sq; redf[1][wid] = mx; }
        __syncthreads();
        if (t == 0) {
            float ssq = 0.f, smx = 0.f;
            #pragma unroll
            for (int i = 0; i < WAVES; ++i) { ssq += redf[0][i]; smx = fmaxf(smx, redf[1][i]); }
            atomicAdd(&ws[OFF_SUMM2], ssq);
            atomicMax((unsigned int*)ws + OFF_MAXM, __float_as_uint(smx));
        }
    }
}

__global__ __launch_bounds__(256) void k_final(float* ws, float* out) {
    __shared__ double redn[4], redd[4];
    const int b = blockIdx.x;
    const int t = threadIdx.x;
    const int wid = t >> 6, lane = t & 63;
    const float* rowsum = ws + OFF_ROWSUM + (size_t)b * N;
    double num = 0.0, den = 0.0;
    #pragma unroll
    for (int q = 0; q < 4; ++q) {
        int j = t + 256 * q;
        double r = (double)rowsum[j];
        float ct = 0.f;
        #pragma unroll
        for (int rep = 0; rep < NREP; ++rep)
            ct += ws[OFF_COLT + (size_t)(b * NREP + rep) * N + j];
        num += (double)ws[OFF_COLSUMM + j] * r;
        den += (double)ct * r;
    }
    #pragma unroll
    for (int o = 32; o > 0; o >>= 1) {
        num += __shfl_down(num, o, 64);
        den += __shfl_down(den, o, 64);
    }
    if (lane == 0) { redn[wid] = num; redd[wid] = den; }
    __syncthreads();
    if (t == 0) {
        double NUM = redn[0] + redn[1] + redn[2] + redn[3];
        double DEN = redd[0] + redd[1] + redd[2] + redd[3];
        double mu = NUM / DEN;
        double r = (double)ws[OFF_SUMM2] - 2.0 * mu * (double)ws[OFF_SUMMT + b]
                 + mu * mu * (double)ws[OFF_SUMTT + b];
        float mx = ws[OFF_MAXM];  // float bits written via uint atomicMax
        double norm = 1048576.0 * (double)mx * (double)mx;
        atomicAdd(out, (float)(sqrt(r / norm) / 8.0));
    }
}

extern "C" void kernel_launch(void* const* d_in, const int* in_sizes, int n_in,
                              void* d_out, int out_size, void* d_ws, size_t ws_size,
                              hipStream_t stream) {
    const float* pred = (const float*)d_in[0];   // [8, 2048]
    const float* M = (const float*)d_in[2];      // [1024, 1024]
    float* ws = (float*)d_ws;
    float* out = (float*)d_out;

    hipMemsetAsync(ws + ZERO_START, 0, (size_t)(WS_END - ZERO_START) * sizeof(float), stream);
    hipMemsetAsync(out, 0, sizeof(float), stream);
    k_prep<<<9, 256, 0, stream>>>(ws);
    dim3 grid(CHUNKS, B_);
    k_row<<<grid, T_, 0, stream>>>(pred, M, ws);
    k_final<<<B_, 256, 0, stream>>>(ws, out);
}

// Round 12
// 102.760 us; speedup vs baseline: 1.2507x; 1.2507x over previous
//
#include <hip/hip_runtime.h>
#include <math.h>

#define N 1024
#define B_ 8
#define T_ 512
#define NREP 4
#define CHUNKS 32

// ws layout (float index)
#define OFF_SF      0        // 1024 x float2 (element shift factor)
#define OFF_TA      2048     // 16(k1) x 64(lane) x float2 : W_1024^{lane*k1}
#define OFF_TB      4096     // 16(k2) x 4(n3) x float2    : W_64^{n3*k2}
#define OFF_ROWSUM  4224     // 8 x 1024
#define ZERO_START  12416
#define OFF_COLSUMM 12416    // 1024
#define OFF_SUMM2   13440
#define OFF_MAXM    13441
#define OFF_SUMMT   13448    // 8
#define OFF_SUMTT   13456    // 8
#define OFF_COLT    13464    // 8 batches x NREP x 1024
#define WS_END      (OFF_COLT + B_ * NREP * N)

// packed fp32 pair (re,im) — clang lowers <2 x float> arithmetic to v_pk_*_f32
typedef float f2 __attribute__((ext_vector_type(2)));
__device__ __forceinline__ f2 mkf2(float a, float b) { f2 r; r.x = a; r.y = b; return r; }

__device__ __forceinline__ f2 cmulv(f2 a, f2 b) {
    f2 p = mkf2(a.x, a.x) * b;                 // (ax bx, ax by)
    f2 q = mkf2(a.y, a.y) * mkf2(b.y, b.x);    // (ay by, ay bx)
    return mkf2(p.x - q.x, p.y + q.y);
}

// 4-pt DFT (W4 = -i), in place, packed complex
__device__ __forceinline__ void dft4v(f2& a0, f2& a1, f2& a2, f2& a3) {
    f2 e0 = a0 + a2, e1 = a0 - a2, e2 = a1 + a3, e3 = a1 - a3;
    a0 = e0 + e2;
    a2 = e0 - e2;
    a1 = mkf2(e1.x + e3.y, e1.y - e3.x);   // e1 - i*e3
    a3 = mkf2(e1.x - e3.y, e1.y + e3.x);   // e1 + i*e3
}

// 16-pt DFT over register index n (natural order in).
// Output: slot r = 4c+d holds S[k = c+4d]  (digit-swapped order).
__device__ __forceinline__ void dft16v(f2 x[16]) {
    #pragma unroll
    for (int b = 0; b < 4; ++b) dft4v(x[b], x[4 + b], x[8 + b], x[12 + b]);
    const float C1 = 0.9238795325112867f, S1 = 0.3826834323650898f;
    const float C2 = 0.7071067811865476f;
    x[5]  = cmulv(x[5],  mkf2( C1, -S1));   // bc=1
    x[6]  = cmulv(x[6],  mkf2( C2, -C2));   // bc=2
    x[7]  = cmulv(x[7],  mkf2( S1, -C1));   // bc=3
    x[9]  = cmulv(x[9],  mkf2( C2, -C2));   // bc=2
    x[10] = mkf2(x[10].y, -x[10].x);        // bc=4 : * (0,-1)
    x[11] = cmulv(x[11], mkf2(-C2, -C2));   // bc=6
    x[13] = cmulv(x[13], mkf2( S1, -C1));   // bc=3
    x[14] = cmulv(x[14], mkf2(-C2, -C2));   // bc=6
    x[15] = cmulv(x[15], mkf2(-C1,  S1));   // bc=9
    #pragma unroll
    for (int c = 0; c < 4; ++c) dft4v(x[4*c], x[4*c+1], x[4*c+2], x[4*c+3]);
}

__device__ __forceinline__ float wave_sum(float v) {
    #pragma unroll
    for (int o = 32; o > 0; o >>= 1) v += __shfl_down(v, o, 64);
    return v;
}
__device__ __forceinline__ float wave_max(float v) {
    #pragma unroll
    for (int o = 32; o > 0; o >>= 1) v = fmaxf(v, __shfl_down(v, o, 64));
    return v;
}

// DPP quad-perm move (cross-lane within each 4-lane quad), VALU-only
template<int CTRL>
__device__ __forceinline__ float dppf(float x) {
    return __int_as_float(__builtin_amdgcn_update_dpp(
        0, __float_as_int(x), CTRL, 0xF, 0xF, true));
}
#define DPP_XOR1 0xB1   // quad_perm [1,0,3,2]
#define DPP_XOR2 0x4E   // quad_perm [2,3,0,1]

// trig tables + ws zeroing + out zeroing (no separate memsets -> 2 fewer
// dispatches): 9 blocks x 256 threads
__global__ __launch_bounds__(256) void k_prep(float* ws, float* out) {
    const int e = blockIdx.x * 256 + threadIdx.x;   // 0..2303
    if (e < 1024) {
        double ang = -2.0 * 337.927 * 1.5 * (double)(e - 512);
        double s, c;
        sincos(ang, &s, &c);
        ws[OFF_SF + 2 * e]     = (float)c;
        ws[OFF_SF + 2 * e + 1] = (float)s;
    } else if (e < 2048) {
        int e2 = e - 1024;
        int k1 = e2 >> 6, uu = e2 & 63;
        double ang = -2.0 * M_PI * (double)(uu * k1) / 1024.0;
        double s, c;
        sincos(ang, &s, &c);
        ws[OFF_TA + 2 * e2]     = (float)c;
        ws[OFF_TA + 2 * e2 + 1] = (float)s;
    } else if (e < 2112) {
        int e2 = e - 2048;
        int k2 = e2 >> 2, n3 = e2 & 3;
        double ang = -2.0 * M_PI * (double)(n3 * k2) / 64.0;
        double s, c;
        sincos(ang, &s, &c);
        ws[OFF_TB + 2 * e2]     = (float)c;
        ws[OFF_TB + 2 * e2 + 1] = (float)s;
    }
    for (int j = ZERO_START + e; j < WS_END; j += 9 * 256) ws[j] = 0.f;
    if (e == 0) out[0] = 0.f;
}

// CLEAN WG-count A/B (r11 was spill-confounded: T=1024 -> VGPR 64 -> 63 MB
// scratch). This round keeps the ONLY spill-free config (T=512, wpe(2,4))
// and halves WGs vs r10 by doing 2 rows/wave: grid (32,8) = 256 WGs.
// Per-CU row count identical to r10; only WG count changes.
//   per-WG-overhead theory -> k_row ~24-32 µs; per-row-work theory -> ~46-52.
// Wave wid does rows m = 16*cnk + 2*wid + rr (rr=0,1); (cnk0,wid0) adds m=512.
// Stats tail: block gid scans M rows 4gid..4gid+3 (uniform, each element once).
__global__ __attribute__((amdgpu_flat_work_group_size(T_, T_), amdgpu_waves_per_eu(2, 4)))
void k_row(const float* __restrict__ pred,
           const float* __restrict__ M,
           float* __restrict__ ws) {
    __shared__ f2   Y2[N];            // 8 KB   y interleaved
    __shared__ f2   Ysf[N];           // 8 KB   y * shiftfactor
    __shared__ f2   taL[N];           // 8 KB   W_1024^{u*k1} table
    __shared__ f2   TPh[8][N / 2];    // 32 KB  per-wave half transpose buffers
    __shared__ f2   TB2[64];          // 0.5 KB W_64^{n3*k2}
    __shared__ float colAcc[N];       // 4 KB   block column accumulator
    __shared__ float redf[2][8];
    const int t = threadIdx.x;
    const int cnk = blockIdx.x;
    const int b = blockIdx.y;
    const int wid = t >> 6, u = t & 63;

    // ---- staging: y, y*sf, ta table into LDS; colAcc zero ----
    {
        const float* pr = pred + (size_t)b * 2 * N;
        float2 re = *(const float2*)(pr + 2 * t);
        float2 im = *(const float2*)(pr + N + 2 * t);
        const f2* g = (const f2*)ws;
        f2 y0 = mkf2(re.x, im.x), y1 = mkf2(re.y, im.y);
        Y2[2 * t]     = y0;
        Y2[2 * t + 1] = y1;
        Ysf[2 * t]     = cmulv(y0, g[OFF_SF / 2 + 2 * t]);
        Ysf[2 * t + 1] = cmulv(y1, g[OFF_SF / 2 + 2 * t + 1]);
        taL[t]       = g[OFF_TA / 2 + t];
        taL[t + 512] = g[OFF_TA / 2 + t + 512];
        if (t < 64) TB2[t] = g[OFF_TB / 2 + t];
        colAcc[t] = 0.f;
        colAcc[t + 512] = 0.f;
    }
    __syncthreads();

    const int k1u = u >> 2;
    const int n3 = u & 3;
    const int k3 = ((u & 1) << 1) | ((u >> 1) & 1);   // bitrev2(n3)
    const int clane = (k1u | (k3 << 8)) ^ 512;        // output column base (incl. fftshift)
    const bool hi2 = (u & 2) != 0;
    const bool odd = (u & 1) != 0;
    f2* tp = TPh[wid];

    float mtl = 0.f, ttl = 0.f;
    const int nrow = (cnk == 0 && wid == 0) ? 3 : 2;

    for (int rr = 0; rr < nrow; ++rr) {
        const int m = (rr < 2) ? (cnk * 16 + 2 * wid + rr) : 512;
        const int mm = (N - m) & (N - 1);
        const bool domm = (mm != m);
        const float w = domm ? 2.f : 1.f;
        const float mmw = domm ? 1.f : 0.f;

        f2 x[16];
        // phase A: product (ysf[j]*y[s]) + radix-16 over n1 — all LDS, packed
        const int sbase = (u - m + 512) & (N - 1);
        #pragma unroll
        for (int n1 = 0; n1 < 16; ++n1) {
            int j = (n1 << 6) + u;
            int s = (sbase + (n1 << 6)) & (N - 1);
            x[n1] = cmulv(Ysf[j], Y2[s]);
        }
        dft16v(x);
        #pragma unroll
        for (int r = 1; r < 16; ++r) {
            int k1 = ((r & 3) << 2) | (r >> 2);
            x[r] = cmulv(x[r], taL[(k1 << 6) + u]);
        }

        // wave-local transpose in two k1-halves through a 4 KB/wave buffer
        f2 yv[16];
        asm volatile("s_waitcnt lgkmcnt(0)" ::: "memory");   // WAR vs prev row reads
        #pragma unroll
        for (int r = 0; r < 16; ++r) if ((r & 3) < 2) {      // k1 = 0..7
            int k1 = ((r & 3) << 2) | (r >> 2);
            int el = ((k1 & 7) << 6) | (((k1u ^ k1) & 15) << 2) | n3;
            tp[el] = x[r];
        }
        asm volatile("s_waitcnt lgkmcnt(0)" ::: "memory");   // RAW write->read
        if (u < 32) {                                         // lanes with k1u<8
            #pragma unroll
            for (int n2 = 0; n2 < 16; ++n2) {
                int el = ((k1u & 7) << 6) | (((n2 ^ k1u) & 15) << 2) | n3;
                yv[n2] = tp[el];
            }
        }
        asm volatile("s_waitcnt lgkmcnt(0)" ::: "memory");   // reads done before overwrite
        #pragma unroll
        for (int r = 0; r < 16; ++r) if ((r & 3) >= 2) {     // k1 = 8..15
            int k1 = ((r & 3) << 2) | (r >> 2);
            int el = ((k1 & 7) << 6) | (((k1u ^ k1) & 15) << 2) | n3;
            tp[el] = x[r];
        }
        asm volatile("s_waitcnt lgkmcnt(0)" ::: "memory");
        if (u >= 32) {                                        // lanes with k1u>=8
            #pragma unroll
            for (int n2 = 0; n2 < 16; ++n2) {
                int el = ((k1u & 7) << 6) | (((n2 ^ k1u) & 15) << 2) | n3;
                yv[n2] = tp[el];
            }
        }

        // phase B: radix-16 over n2 + W_64^{n3*k2} — packed
        dft16v(yv);
        #pragma unroll
        for (int r = 1; r < 16; ++r) {
            int k2 = ((r & 3) << 2) | (r >> 2);
            yv[r] = cmulv(yv[r], TB2[(k2 << 2) | n3]);
        }

        // phase C: radix-4 across quad lanes (DPP) + magnitude + reductions.
        // M loaded inline (compiler schedules freely) — r8-proven.
        const float* Mrow  = M + (size_t)m * N + clane;
        const float* Mrow2 = M + (size_t)mm * N + clane;
        const float w225 = w * 2.25f;
        float rs = 0.f;
        #pragma unroll
        for (int r = 0; r < 16; ++r) {
            int k2 = ((r & 3) << 2) | (r >> 2);
            float ar = yv[r].x, ai = yv[r].y;
            float br = dppf<DPP_XOR2>(ar), bi = dppf<DPP_XOR2>(ai);
            float zr = hi2 ? (br - ar) : (ar + br);
            float zi = hi2 ? (bi - ai) : (ai + bi);
            float qr = dppf<DPP_XOR1>(zr), qi = dppf<DPP_XOR1>(zi);
            float Xr = odd ? (qr - (hi2 ? zi : zr)) : (zr + (hi2 ? qi : qr));
            float Xi = odd ? (qi + (hi2 ? zr : -zi)) : (zi + (hi2 ? -qr : qi));
            float mag2 = Xr * Xr + Xi * Xi;
            float v = 1.5f * sqrtf(mag2);
            rs  += v;
            ttl += w225 * mag2;                 // w * v^2
            float ms = Mrow[k2 << 4] + mmw * Mrow2[k2 << 4];
            mtl += ms * v;
            int cc = clane + (k2 << 4);
            atomicAdd(&colAcc[cc ^ ((cc >> 4) & 16)], w * v);  // 2-way bank alias: free
        }
        rs = wave_sum(rs);
        if (u == 0) {
            ws[OFF_ROWSUM + (size_t)b * N + m] = rs;
            if (domm) ws[OFF_ROWSUM + (size_t)b * N + mm] = rs;
        }
    }

    // block epilogue: MT/TT block-reduce + colAcc flush (1 global atomic/column)
    mtl = wave_sum(mtl);
    ttl = wave_sum(ttl);
    if (u == 0) { redf[0][wid] = mtl; redf[1][wid] = ttl; }
    __syncthreads();
    if (t == 0) {
        float smt = 0.f, stt = 0.f;
        #pragma unroll
        for (int i = 0; i < 8; ++i) { smt += redf[0][i]; stt += redf[1][i]; }
        atomicAdd(&ws[OFF_SUMMT + b], smt);
        atomicAdd(&ws[OFF_SUMTT + b], stt);
    }
    {
        float* colT = ws + OFF_COLT + (size_t)(b * NREP + (cnk & (NREP - 1))) * N;
        int j = t;
        atomicAdd(&colT[j], colAcc[j ^ ((j >> 4) & 16)]);
        j = t + 512;
        atomicAdd(&colT[j], colAcc[j ^ ((j >> 4) & 16)]);
    }

    // ---- uniform M-stats tail: this block scans M rows 4*gid .. 4*gid+3 ----
    {
        const int gid = b * CHUNKS + cnk;            // 0..255
        const float* s0 = M + (size_t)(4 * gid) * N;
        float a0 = s0[t],         a1 = s0[t + 512];
        float b0 = s0[N + t],     b1 = s0[N + t + 512];
        float c0 = s0[2 * N + t], c1 = s0[2 * N + t + 512];
        float d0 = s0[3 * N + t], d1 = s0[3 * N + t + 512];
        atomicAdd(&ws[OFF_COLSUMM + t],       a0 + b0 + c0 + d0);
        atomicAdd(&ws[OFF_COLSUMM + t + 512], a1 + b1 + c1 + d1);
        float sq = a0 * a0 + a1 * a1 + b0 * b0 + b1 * b1
                 + c0 * c0 + c1 * c1 + d0 * d0 + d1 * d1;
        float mx = fmaxf(fmaxf(fmaxf(a0, a1), fmaxf(b0, b1)),
                         fmaxf(fmaxf(c0, c1), fmaxf(d0, d1)));
        sq = wave_sum(sq);
        mx = wave_max(mx);
        __syncthreads();                              // t0 done reading redf above
        if (u == 0) { redf[0][wid] = sq; redf[1][wid] = mx; }
        __syncthreads();
        if (t == 0) {
            float ssq = 0.f, smx = 0.f;
            #pragma unroll
            for (int i = 0; i < 8; ++i) { ssq += redf[0][i]; smx = fmaxf(smx, redf[1][i]); }
            atomicAdd(&ws[OFF_SUMM2], ssq);
            atomicMax((unsigned int*)ws + OFF_MAXM, __float_as_uint(smx));
        }
    }
}

__global__ __launch_bounds__(256) void k_final(float* ws, float* out) {
    __shared__ double redn[4], redd[4];
    const int b = blockIdx.x;
    const int t = threadIdx.x;
    const int wid = t >> 6, lane = t & 63;
    const float* rowsum = ws + OFF_ROWSUM + (size_t)b * N;
    double num = 0.0, den = 0.0;
    #pragma unroll
    for (int q = 0; q < 4; ++q) {
        int j = t + 256 * q;
        double r = (double)rowsum[j];
        float ct = 0.f;
        #pragma unroll
        for (int rep = 0; rep < NREP; ++rep)
            ct += ws[OFF_COLT + (size_t)(b * NREP + rep) * N + j];
        num += (double)ws[OFF_COLSUMM + j] * r;
        den += (double)ct * r;
    }
    #pragma unroll
    for (int o = 32; o > 0; o >>= 1) {
        num += __shfl_down(num, o, 64);
        den += __shfl_down(den, o, 64);
    }
    if (lane == 0) { redn[wid] = num; redd[wid] = den; }
    __syncthreads();
    if (t == 0) {
        double NUM = redn[0] + redn[1] + redn[2] + redn[3];
        double DEN = redd[0] + redd[1] + redd[2] + redd[3];
        double mu = NUM / DEN;
        double r = (double)ws[OFF_SUMM2] - 2.0 * mu * (double)ws[OFF_SUMMT + b]
                 + mu * mu * (double)ws[OFF_SUMTT + b];
        float mx = ws[OFF_MAXM];  // float bits written via uint atomicMax
        double norm = 1048576.0 * (double)mx * (double)mx;
        atomicAdd(out, (float)(sqrt(r / norm) / 8.0));
    }
}

extern "C" void kernel_launch(void* const* d_in, const int* in_sizes, int n_in,
                              void* d_out, int out_size, void* d_ws, size_t ws_size,
                              hipStream_t stream) {
    const float* pred = (const float*)d_in[0];   // [8, 2048]
    const float* M = (const float*)d_in[2];      // [1024, 1024]
    float* ws = (float*)d_ws;
    float* out = (float*)d_out;

    k_prep<<<9, 256, 0, stream>>>(ws, out);
    dim3 grid(CHUNKS, B_);
    k_row<<<grid, T_, 0, stream>>>(pred, M, ws);
    k_final<<<B_, 256, 0, stream>>>(ws, out);
}